// Round 11
// baseline (462.436 us; speedup 1.0000x reference)
//
#include <hip/hip_runtime.h>
#include <hip/hip_bf16.h>
#include <math.h>

// Problem constants
#define B_SZ   4096
#define NCAND  32
#define DIN    256
#define E_SZ   128
#define H_SZ   512
#define VOCAB  32
#define LN_EPS 1e-5f

typedef unsigned short u16;
typedef unsigned int   u32;
typedef __attribute__((ext_vector_type(8))) short  short8;   // 8 bf16 (4 VGPR)
typedef __attribute__((ext_vector_type(4))) float  floatx4;  // MFMA acc

static __device__ __forceinline__ float sigmoidf_(float x) {
    return 1.0f / (1.0f + expf(-x));
}
// fp32 -> bf16 (RNE), finite inputs
static __device__ __forceinline__ u16 f2bf(float x) {
    u32 u = __float_as_uint(x);
    return (u16)((u + 0x7FFFu + ((u >> 16) & 1u)) >> 16);
}
static __device__ __forceinline__ float bfbits2f(u16 h) {
    return __uint_as_float(((u32)h) << 16);
}

// async 16B global->LDS (DMA; LDS dest = wave-uniform base + lane*16)
typedef const __attribute__((address_space(1))) unsigned int* gas_ptr;
typedef __attribute__((address_space(3)))       unsigned int* las_ptr;
static __device__ __forceinline__ void gload_lds16(const u16* g, u16* l) {
    __builtin_amdgcn_global_load_lds((gas_ptr)(const void*)g, (las_ptr)(void*)l, 16, 0, 0);
}

// Load 8 fp32, split into hi/lo bf16, store 16B each.
static __device__ __forceinline__ void split_store8(const float* __restrict__ g,
                                                    u16* __restrict__ sh,
                                                    u16* __restrict__ sl)
{
    float4 a = *(const float4*)g;
    float4 b = *(const float4*)(g + 4);
    float v[8] = {a.x, a.y, a.z, a.w, b.x, b.y, b.z, b.w};
    union { u16 us[8]; uint4 q; } hb, lb;
    #pragma unroll
    for (int j = 0; j < 8; ++j) {
        u16 h = f2bf(v[j]);
        hb.us[j] = h;
        lb.us[j] = f2bf(v[j] - bfbits2f(h));
    }
    *(uint4*)sh = hb.q;
    *(uint4*)sl = lb.q;
}

// Blocked "LDS-image" index for element (row r, col/k):
//   idx = (rtile*KT + k/32)*4096 + (r&127)*32 + (k&31)
// Each 4096-u16 image = one 128x32 linear staging tile.

// ---------------------------------------------------------------------------
// Weight prep: blocked split images from [W1 | W2] (K x N1, K x N2), N-major
// ---------------------------------------------------------------------------
__global__ __launch_bounds__(256)
void transpose_split_w(const float* __restrict__ W1, const float* __restrict__ W2,
                       int N1, int N2, int K,
                       u16* __restrict__ Wt_hi, u16* __restrict__ Wt_lo)
{
    __shared__ float t[64][68];
    const int n0 = blockIdx.x * 64, k0 = blockIdx.y * 64;
    const int tid = threadIdx.x;
    const int KT = K >> 5;

    {
        const int kl = tid >> 4, nl4 = (tid & 15) * 4;
        const int ng = n0 + nl4;
        const float* src; int col, ld;
        if (ng < N1) { src = W1; col = ng;      ld = N1; }
        else         { src = W2; col = ng - N1; ld = N2; }
        #pragma unroll
        for (int p = 0; p < 4; ++p) {
            float4 v = *(const float4*)(src + (size_t)(k0 + kl + p * 16) * ld + col);
            *(float4*)&t[kl + p * 16][nl4] = v;
        }
    }
    __syncthreads();

    const int nl = tid >> 2, kc = tid & 3;
    union { u16 us[16]; uint4 v[2]; } hb, lb;
    #pragma unroll
    for (int j = 0; j < 16; ++j) {
        float x = t[kc * 16 + j][nl];
        u16 h = f2bf(x);
        float r = x - bfbits2f(h);
        hb.us[j] = h;
        lb.us[j] = f2bf(r);
    }
    const int n  = n0 + nl;
    const int kb = k0 + kc * 16;               // multiple of 16
    const size_t off = ((size_t)(n >> 7) * KT + (kb >> 5)) * 4096
                     + (size_t)(n & 127) * 32 + (kb & 31);
    *(uint4*)(Wt_hi + off)     = hb.v[0];
    *(uint4*)(Wt_hi + off + 8) = hb.v[1];
    *(uint4*)(Wt_lo + off)     = lb.v[0];
    *(uint4*)(Wt_lo + off + 8) = lb.v[1];
}

// All four bias concats in one launch
__global__ __launch_bounds__(256)
void bias_cat4_kernel(const float* __restrict__ a0, const float* __restrict__ c0, float* __restrict__ o0,
                      const float* __restrict__ a1, const float* __restrict__ c1, float* __restrict__ o1,
                      const float* __restrict__ a2, const float* __restrict__ c2, float* __restrict__ o2,
                      const float* __restrict__ a3, const float* __restrict__ c3, float* __restrict__ o3)
{
    const int t = blockIdx.x * 256 + threadIdx.x;      // 0..6143
    const int w = t / 1536;
    const int i = t - w * 1536;
    const float* a; const float* c; float* o;
    if      (w == 0) { a = a0; c = c0; o = o0; }
    else if (w == 1) { a = a1; c = c1; o = o1; }
    else if (w == 2) { a = a2; c = c2; o = o2; }
    else             { a = a3; c = c3; o = o3; }
    o[i] = (i < 1024) ? a[i] : c[i - 1024];
}

// fp32 [M][512] row-major -> blocked split images (KT=16). grid = M*64/256.
__global__ __launch_bounds__(256)
void split_blocked_kernel(const float* __restrict__ src,
                          u16* __restrict__ hi, u16* __restrict__ lo)
{
    const int i = blockIdx.x * 256 + threadIdx.x;
    const int m = i >> 6, kq = (i & 63) << 3;
    const size_t idx = ((size_t)(m >> 7) * 16 + (kq >> 5)) * 4096
                     + (size_t)(m & 127) * 32 + (kq & 31);
    split_store8(src + (size_t)m * 512 + kq, &hi[idx], &lo[idx]);
}

// ---------------------------------------------------------------------------
// Dual split-bf16 MFMA GEMM. A fragments load DIRECTLY from global (L2-hot
// blocked image, per-lane 16B chunks) -> LDS carries only W (double-buffered
// 16 KB). Halves per-k-step LDS traffic (96 -> 48 KB) in an LDS-BW-bound
// loop. Unroll-2 over k-tiles (KT=12/16 both even) gives compile-time
// register-set alternation for the A prefetch (no runtime-indexed regs).
//   C(4096x1536) = A @ W^T + bias ; acc += Ah*Wh + Ah*Wl + Al*Wh
// 1D grid of 768 blocks, XCD-chunked swizzle (bijective). Operand values and
// MFMA order identical to the all-LDS version -> bit-identical results.
// ---------------------------------------------------------------------------
__global__ __launch_bounds__(256)
void mfma_gemm_dual_kernel(const u16* __restrict__ Axh, const u16* __restrict__ Axl,
                           const u16* __restrict__ Wxh, const u16* __restrict__ Wxl,
                           const float* __restrict__ bx, float* __restrict__ Cx, int KTx,
                           const u16* __restrict__ Ahh, const u16* __restrict__ Ahl,
                           const u16* __restrict__ Whh, const u16* __restrict__ Whl,
                           const float* __restrict__ bh, float* __restrict__ Ch, int KTh)
{
    __shared__ __align__(16) u16 sWh[2][4096];
    __shared__ __align__(16) u16 sWl[2][4096];

    const int tid  = threadIdx.x;
    const int lane = tid & 63;
    const int wave = tid >> 6;
    const int wm = (wave >> 1) * 64;
    const int wn = (wave & 1) * 64;
    const int r16 = lane & 15;
    const int q8  = (lane >> 4) * 8;

    // XCD-chunk swizzle: 768 blocks = 8 XCDs x 96 (bijective: f=8q+r -> r*96+q)
    const int f   = blockIdx.x;
    const int lin = (f & 7) * 96 + (f >> 3);
    const int sel = lin >= 384;
    const int r   = lin - (sel ? 384 : 0);       // 0..383
    const int mt  = r / 12;
    const int nt  = r - mt * 12;
    const int m_base = mt * 128;
    const int n_base = nt * 128;

    const u16* Ah_  = sel ? Ahh : Axh;
    const u16* Al_  = sel ? Ahl : Axl;
    const u16* Wh_  = sel ? Whh : Wxh;
    const u16* Wl_  = sel ? Whl : Wxl;
    const float* bias = sel ? bh : bx;
    float*       C    = sel ? Ch : Cx;
    const int    KT   = sel ? KTh : KTx;

    const u16* Ah0 = Ah_ + (size_t)(m_base >> 7) * KT * 4096;
    const u16* Al0 = Al_ + (size_t)(m_base >> 7) * KT * 4096;
    const size_t wbase = (size_t)(n_base >> 7) * KT * 4096;
    const int sofs = wave * 1024;            // this wave's quarter of each W image
    const int gofs = sofs + (lane << 3);     // per-lane 16B chunk (u16 units)

    // per-lane A fragment offsets within one 128x32 k-tile image
    int aoff[4];
    #pragma unroll
    for (int i = 0; i < 4; ++i) aoff[i] = (wm + i * 16 + r16) * 32 + q8;

    // W fragment LDS offsets
    int boff[4];
    #pragma unroll
    for (int i = 0; i < 4; ++i) boff[i] = (wn + i * 16 + r16) * 32 + q8;

    floatx4 acc[4][4] = {};

    short8 aAh[4], aAl[4];   // register set A (even k-tiles)
    short8 aBh[4], aBl[4];   // register set B (odd k-tiles)

    // prologue: DMA W(0) into buf0; load A(0) into set A
    {
        const size_t wi = wbase + gofs;
        gload_lds16(Wh_ + wi,       &sWh[0][sofs]);
        gload_lds16(Wh_ + wi + 512, &sWh[0][sofs + 512]);
        gload_lds16(Wl_ + wi,       &sWl[0][sofs]);
        gload_lds16(Wl_ + wi + 512, &sWl[0][sofs + 512]);
        #pragma unroll
        for (int i = 0; i < 4; ++i) {
            aAh[i] = *(const short8*)(Ah0 + aoff[i]);
            aAl[i] = *(const short8*)(Al0 + aoff[i]);
        }
    }

    for (int kt = 0; kt < KT; kt += 2) {
        // ---- even tile kt: W in buf0, A in set A ----
        __syncthreads();   // drains vmcnt(0): W(kt) staged; buf1 reads done

        {   // stage W(kt+1) -> buf1 ; prefetch A(kt+1) -> set B  (kt+1 <= KT-1)
            const size_t wi = wbase + (size_t)(kt + 1) * 4096 + gofs;
            gload_lds16(Wh_ + wi,       &sWh[1][sofs]);
            gload_lds16(Wh_ + wi + 512, &sWh[1][sofs + 512]);
            gload_lds16(Wl_ + wi,       &sWl[1][sofs]);
            gload_lds16(Wl_ + wi + 512, &sWl[1][sofs + 512]);
            const size_t ai = (size_t)(kt + 1) * 4096;
            #pragma unroll
            for (int i = 0; i < 4; ++i) {
                aBh[i] = *(const short8*)(Ah0 + ai + aoff[i]);
                aBl[i] = *(const short8*)(Al0 + ai + aoff[i]);
            }
        }
        {
            short8 bhf[4], blf[4];
            #pragma unroll
            for (int i = 0; i < 4; ++i) {
                bhf[i] = *(const short8*)&sWh[0][boff[i]];
                blf[i] = *(const short8*)&sWl[0][boff[i]];
            }
            #pragma unroll
            for (int i = 0; i < 4; ++i)
                #pragma unroll
                for (int j = 0; j < 4; ++j) {
                    acc[i][j] = __builtin_amdgcn_mfma_f32_16x16x32_bf16(aAh[i], bhf[j], acc[i][j], 0, 0, 0);
                    acc[i][j] = __builtin_amdgcn_mfma_f32_16x16x32_bf16(aAh[i], blf[j], acc[i][j], 0, 0, 0);
                    acc[i][j] = __builtin_amdgcn_mfma_f32_16x16x32_bf16(aAl[i], bhf[j], acc[i][j], 0, 0, 0);
                }
        }

        // ---- odd tile kt+1: W in buf1, A in set B ----
        __syncthreads();   // drains vmcnt(0): W(kt+1) staged; buf0 reads done

        if (kt + 2 < KT) { // stage W(kt+2) -> buf0 ; prefetch A(kt+2) -> set A
            const size_t wi = wbase + (size_t)(kt + 2) * 4096 + gofs;
            gload_lds16(Wh_ + wi,       &sWh[0][sofs]);
            gload_lds16(Wh_ + wi + 512, &sWh[0][sofs + 512]);
            gload_lds16(Wl_ + wi,       &sWl[0][sofs]);
            gload_lds16(Wl_ + wi + 512, &sWl[0][sofs + 512]);
            const size_t ai = (size_t)(kt + 2) * 4096;
            #pragma unroll
            for (int i = 0; i < 4; ++i) {
                aAh[i] = *(const short8*)(Ah0 + ai + aoff[i]);
                aAl[i] = *(const short8*)(Al0 + ai + aoff[i]);
            }
        }
        {
            short8 bhf[4], blf[4];
            #pragma unroll
            for (int i = 0; i < 4; ++i) {
                bhf[i] = *(const short8*)&sWh[1][boff[i]];
                blf[i] = *(const short8*)&sWl[1][boff[i]];
            }
            #pragma unroll
            for (int i = 0; i < 4; ++i)
                #pragma unroll
                for (int j = 0; j < 4; ++j) {
                    acc[i][j] = __builtin_amdgcn_mfma_f32_16x16x32_bf16(aBh[i], bhf[j], acc[i][j], 0, 0, 0);
                    acc[i][j] = __builtin_amdgcn_mfma_f32_16x16x32_bf16(aBh[i], blf[j], acc[i][j], 0, 0, 0);
                    acc[i][j] = __builtin_amdgcn_mfma_f32_16x16x32_bf16(aBl[i], bhf[j], acc[i][j], 0, 0, 0);
                }
        }
    }

    // epilogue: C/D mapping col=lane&15, row=(lane>>4)*4+reg
    const int quad = lane >> 4;
    #pragma unroll
    for (int j = 0; j < 4; ++j) {
        const int n = n_base + wn + j * 16 + r16;
        const float bv = bias[n];
        #pragma unroll
        for (int i = 0; i < 4; ++i) {
            #pragma unroll
            for (int rr = 0; rr < 4; ++rr) {
                const int m = m_base + wm + i * 16 + quad * 4 + rr;
                C[(size_t)m * 1536 + n] = acc[i][j][rr] + bv;
            }
        }
    }
}

// ---------------------------------------------------------------------------
// q = A(MxK) @ Bt(NxK)^T. 64x64x16 tiles, 4x4 micro. (q = snd @ Wk^T)
// ---------------------------------------------------------------------------
__global__ __launch_bounds__(256)
void gemm_bt64_kernel(const float* __restrict__ A, const float* __restrict__ Bt,
                      float* __restrict__ C, int M, int N, int K, int ldc)
{
    __shared__ float As[16][68];
    __shared__ float Bs[16][68];

    const int tid = threadIdx.x;
    const int bm = blockIdx.y * 64;
    const int bn = blockIdx.x * 64;
    const int tx = tid & 15, ty = tid >> 4;
    const int m0 = ty * 4, n0 = tx * 4;
    const int arow = tid >> 2, acol = (tid & 3) * 4;

    float acc[4][4] = {};

    for (int k0 = 0; k0 < K; k0 += 16) {
        float4 a4 = *(const float4*)(A  + (size_t)(bm + arow) * K + (k0 + acol));
        float4 b4 = *(const float4*)(Bt + (size_t)(bn + arow) * K + (k0 + acol));
        As[acol + 0][arow] = a4.x; As[acol + 1][arow] = a4.y;
        As[acol + 2][arow] = a4.z; As[acol + 3][arow] = a4.w;
        Bs[acol + 0][arow] = b4.x; Bs[acol + 1][arow] = b4.y;
        Bs[acol + 2][arow] = b4.z; Bs[acol + 3][arow] = b4.w;
        __syncthreads();
        #pragma unroll
        for (int k = 0; k < 16; ++k) {
            float4 av = *(const float4*)&As[k][m0];
            float4 bv = *(const float4*)&Bs[k][n0];
            float aa[4] = {av.x, av.y, av.z, av.w};
            float bb[4] = {bv.x, bv.y, bv.z, bv.w};
            #pragma unroll
            for (int i = 0; i < 4; ++i)
                #pragma unroll
                for (int j = 0; j < 4; ++j)
                    acc[i][j] = fmaf(aa[i], bb[j], acc[i][j]);
        }
        __syncthreads();
    }

    #pragma unroll
    for (int i = 0; i < 4; ++i)
        *(float4*)(C + (size_t)(bm + m0 + i) * ldc + bn + n0) =
            make_float4(acc[i][0], acc[i][1], acc[i][2], acc[i][3]);
}

// ---------------------------------------------------------------------------
// fused scores/softmax/cbar + rnn_in tail. STAGE-FREE: co read direct (L3/L2).
// ---------------------------------------------------------------------------
__global__ __launch_bounds__(256)
void attn_ctx_kernel(const float* __restrict__ co, const float* __restrict__ q,
                     const float* __restrict__ snd, const float* __restrict__ pmsg,
                     float* __restrict__ cbar,
                     u16* __restrict__ rinh, u16* __restrict__ rinl)
{
    __shared__ float s_q[DIN];
    __shared__ float s_scores[NCAND];
    __shared__ float s_w[NCAND];

    const int b   = blockIdx.x;
    const int tid = threadIdx.x;
    const float* cob = co + (size_t)b * NCAND * DIN;

    if (tid < DIN) s_q[tid] = q[(size_t)b * DIN + tid];
    __syncthreads();

    // scores[n] = sum_d co[n][d] * q[d]  (8 partials per candidate; co direct)
    {
        const int n = tid >> 3, part = tid & 7;
        const float* con = cob + n * DIN;
        float sc = 0.f;
        #pragma unroll
        for (int qq = 0; qq < 8; ++qq) {
            const int d = part * 4 + qq * 32;
            float4 cv = *(const float4*)(con + d);
            float4 qv = *(const float4*)&s_q[d];
            sc += cv.x * qv.x + cv.y * qv.y + cv.z * qv.z + cv.w * qv.w;
        }
        #pragma unroll
        for (int m = 4; m; m >>= 1) sc += __shfl_xor(sc, m);
        if (part == 0) s_scores[n] = sc;
    }
    __syncthreads();

    // softmax over 32 candidates
    if (tid < NCAND) {
        float s  = s_scores[tid];
        float mx = s;
        #pragma unroll
        for (int m = 16; m; m >>= 1) mx = fmaxf(mx, __shfl_xor(mx, m));
        float e = expf(s - mx);
        float sum = e;
        #pragma unroll
        for (int m = 16; m; m >>= 1) sum += __shfl_xor(sum, m);
        s_w[tid] = e / sum;
    }
    __syncthreads();

    // cbar[d] = sum_n w[n] * co[n][d]  (d = tid; co rows direct, L2-hot)
    {
        float cb = 0.f;
        #pragma unroll
        for (int n = 0; n < NCAND; ++n) cb = fmaf(s_w[n], cob[n * DIN + tid], cb);
        cbar[(size_t)b * DIN + tid] = cb;
    }
    {
        // rnn_in cols 128..383: [snd | pmsg] -> blocked split image
        const float x = (tid < 128) ? snd[(size_t)b * E_SZ + tid]
                                    : pmsg[(size_t)b * E_SZ + (tid - 128)];
        const int d = 128 + tid;
        const u16 h = f2bf(x);
        const u16 l = f2bf(x - bfbits2f(h));
        const size_t idx = ((size_t)(b >> 7) * 12 + (d >> 5)) * 4096
                         + (size_t)(b & 127) * 32 + (d & 31);
        rinh[idx] = h;
        rinl[idx] = l;
    }
}

// ---------------------------------------------------------------------------
// context = cbar @ Wk + bk -> rnn_in cols 0..127 (blocked split image, KT=12)
// 64x64 tiles, grid (2, 64) = 128 blocks.
// ---------------------------------------------------------------------------
__global__ __launch_bounds__(256)
void gemm_ctx_kernel(const float* __restrict__ A, const float* __restrict__ Bm,
                     const float* __restrict__ bias,
                     u16* __restrict__ rinh, u16* __restrict__ rinl)
{
    __shared__ float As[16][68];
    __shared__ float Bs[16][68];

    const int tid = threadIdx.x;
    const int bm = blockIdx.y * 64;
    const int bn = blockIdx.x * 64;
    const int tx = tid & 15, ty = tid >> 4;
    const int m0 = ty * 4, n0 = tx * 4;
    const int arow = tid >> 2, acol = (tid & 3) * 4;   // 64 rows x 16 k
    const int brow = tid >> 4, bcol = (tid & 15) * 4;  // 16 k x 64 cols
    const int K = 256, N = 128;

    float acc[4][4] = {};

    for (int k0 = 0; k0 < K; k0 += 16) {
        float4 a4 = *(const float4*)(A + (size_t)(bm + arow) * K + (k0 + acol));
        float4 b4 = *(const float4*)(Bm + (size_t)(k0 + brow) * N + (bn + bcol));
        As[acol + 0][arow] = a4.x; As[acol + 1][arow] = a4.y;
        As[acol + 2][arow] = a4.z; As[acol + 3][arow] = a4.w;
        *(float4*)&Bs[brow][bcol] = b4;
        __syncthreads();
        #pragma unroll
        for (int k = 0; k < 16; ++k) {
            float4 av = *(const float4*)&As[k][m0];
            float4 bv = *(const float4*)&Bs[k][n0];
            float aa[4] = {av.x, av.y, av.z, av.w};
            float bb[4] = {bv.x, bv.y, bv.z, bv.w};
            #pragma unroll
            for (int i = 0; i < 4; ++i)
                #pragma unroll
                for (int j = 0; j < 4; ++j)
                    acc[i][j] = fmaf(aa[i], bb[j], acc[i][j]);
        }
        __syncthreads();
    }

    const float4 bv = *(const float4*)(bias + bn + n0);
    #pragma unroll
    for (int i = 0; i < 4; ++i) {
        float o0 = acc[i][0] + bv.x, o1 = acc[i][1] + bv.y;
        float o2 = acc[i][2] + bv.z, o3 = acc[i][3] + bv.w;
        const int m = bm + m0 + i;
        const int d = bn + n0;                         // multiple of 4, < 128
        const u16 h0 = f2bf(o0), h1 = f2bf(o1), h2 = f2bf(o2), h3 = f2bf(o3);
        const u16 l0 = f2bf(o0 - bfbits2f(h0));
        const u16 l1 = f2bf(o1 - bfbits2f(h1));
        const u16 l2 = f2bf(o2 - bfbits2f(h2));
        const u16 l3 = f2bf(o3 - bfbits2f(h3));
        const size_t idx = ((size_t)(m >> 7) * 12 + (d >> 5)) * 4096
                         + (size_t)(m & 127) * 32 + (d & 31);
        uint2 hv, lv;
        hv.x = (u32)h0 | ((u32)h1 << 16); hv.y = (u32)h2 | ((u32)h3 << 16);
        lv.x = (u32)l0 | ((u32)l1 << 16); lv.y = (u32)l2 | ((u32)l3 << 16);
        *(uint2*)&rinh[idx] = hv;
        *(uint2*)&rinl[idx] = lv;
    }
}

// ---------------------------------------------------------------------------
// LN-GRU combine; optional blocked split image write of new h (KT=16)
// ---------------------------------------------------------------------------
__global__ __launch_bounds__(256)
void gru_combine_kernel(const float* __restrict__ gxc, const float* __restrict__ ghc,
                        const float* __restrict__ hprev, float* __restrict__ hout,
                        u16* __restrict__ himg_hi, u16* __restrict__ himg_lo)
{
    const int b    = blockIdx.x;
    const int tid  = threadIdx.x;
    const int lane = tid & 63, wv = tid >> 6;

    __shared__ float s_part[4][8];
    __shared__ float s_gates[1024];

    const float* gxb = gxc + (size_t)b * 1536;
    const float* ghb = ghc + (size_t)b * 1536;

    const float4 gx4 = *(const float4*)(gxb + tid * 4);
    const float4 gh4 = *(const float4*)(ghb + tid * 4);
    const float2 cx2 = *(const float2*)(gxb + 1024 + tid * 2);
    const float2 ch2 = *(const float2*)(ghb + 1024 + tid * 2);

    float v[8];
    v[0] = gx4.x + gx4.y + gx4.z + gx4.w;
    v[1] = gx4.x*gx4.x + gx4.y*gx4.y + gx4.z*gx4.z + gx4.w*gx4.w;
    v[2] = gh4.x + gh4.y + gh4.z + gh4.w;
    v[3] = gh4.x*gh4.x + gh4.y*gh4.y + gh4.z*gh4.z + gh4.w*gh4.w;
    v[4] = cx2.x + cx2.y;
    v[5] = cx2.x*cx2.x + cx2.y*cx2.y;
    v[6] = ch2.x + ch2.y;
    v[7] = ch2.x*ch2.x + ch2.y*ch2.y;

    #pragma unroll
    for (int i = 0; i < 8; ++i)
        #pragma unroll
        for (int m = 32; m; m >>= 1) v[i] += __shfl_xor(v[i], m);

    if (lane == 0) {
        #pragma unroll
        for (int i = 0; i < 8; ++i) s_part[wv][i] = v[i];
    }
    __syncthreads();

    float t[8];
    #pragma unroll
    for (int i = 0; i < 8; ++i)
        t[i] = s_part[0][i] + s_part[1][i] + s_part[2][i] + s_part[3][i];

    const float mgx = t[0] / 1024.f;
    const float rgx = 1.f / sqrtf(t[1] / 1024.f - mgx * mgx + LN_EPS);
    const float mgh = t[2] / 1024.f;
    const float rgh = 1.f / sqrtf(t[3] / 1024.f - mgh * mgh + LN_EPS);
    const float mcx = t[4] / 512.f;
    const float rcx = 1.f / sqrtf(t[5] / 512.f - mcx * mcx + LN_EPS);
    const float mch = t[6] / 512.f;
    const float rch = 1.f / sqrtf(t[7] / 512.f - mch * mch + LN_EPS);

    float4 g;
    g.x = sigmoidf_((gx4.x - mgx) * rgx + (gh4.x - mgh) * rgh);
    g.y = sigmoidf_((gx4.y - mgx) * rgx + (gh4.y - mgh) * rgh);
    g.z = sigmoidf_((gx4.z - mgx) * rgx + (gh4.z - mgh) * rgh);
    g.w = sigmoidf_((gx4.w - mgx) * rgx + (gh4.w - mgh) * rgh);
    *(float4*)&s_gates[tid * 4] = g;
    __syncthreads();

    const float2 hp2 = *(const float2*)(hprev + (size_t)b * 512 + tid * 2);
    const float z0 = s_gates[tid * 2 + 0];
    const float z1 = s_gates[tid * 2 + 1];
    const float r0 = s_gates[512 + tid * 2 + 0];
    const float r1 = s_gates[512 + tid * 2 + 1];

    const float hh0 = tanhf((cx2.x - mcx) * rcx + r0 * ((ch2.x - mch) * rch));
    const float hh1 = tanhf((cx2.y - mcx) * rcx + r1 * ((ch2.y - mch) * rch));
    const float hn0 = (1.f - z0) * hp2.x + z0 * hh0;
    const float hn1 = (1.f - z1) * hp2.y + z1 * hh1;

    *(float2*)(hout + (size_t)b * 512 + tid * 2) = make_float2(hn0, hn1);

    if (himg_hi) {
        const u16 h0b = f2bf(hn0), h1b = f2bf(hn1);
        const u16 l0b = f2bf(hn0 - bfbits2f(h0b));
        const u16 l1b = f2bf(hn1 - bfbits2f(h1b));
        const int k = tid * 2;
        const size_t idx = ((size_t)(b >> 7) * 16 + (k >> 5)) * 4096
                         + (size_t)(b & 127) * 32 + (k & 31);
        *(u32*)&himg_hi[idx] = (u32)h0b | ((u32)h1b << 16);
        *(u32*)&himg_lo[idx] = (u32)l0b | ((u32)l1b << 16);
    }
}

// ---------------------------------------------------------------------------
// output head
// ---------------------------------------------------------------------------
__global__ __launch_bounds__(256)
void out_kernel(const float* __restrict__ h1, const float* __restrict__ W,
                const float* __restrict__ bias, float* __restrict__ out)
{
    __shared__ float s_h[4][512];
    const int wave = threadIdx.x >> 6, lane = threadIdx.x & 63;
    const int b = blockIdx.x * 4 + wave;

    {
        const float4* hp = (const float4*)(h1 + (size_t)b * 512);
        float4* sp = (float4*)&s_h[wave][0];
        sp[lane]      = hp[lane];
        sp[lane + 64] = hp[lane + 64];
    }
    __syncthreads();

    const int v = lane & 31, half = lane >> 5;
    float acc = 0.f;
    {
        const float* wp = W + (size_t)half * 256 * 32 + v;
        const float* hh = &s_h[wave][half * 256];
        for (int k = 0; k < 256; ++k) acc = fmaf(hh[k], wp[(size_t)k * 32], acc);
    }
    acc += __shfl_xor(acc, 32);
    const float logit = acc + bias[v];

    if (half == 0)
        out[(size_t)3 * B_SZ + (size_t)b * VOCAB + v] = logit;

    float mval = logit; int midx = v;
    #pragma unroll
    for (int m = 16; m; m >>= 1) {
        float ov = __shfl_xor(mval, m);
        int   oi = __shfl_xor(midx, m);
        if (ov > mval || (ov == mval && oi < midx)) { mval = ov; midx = oi; }
    }
    float ex = expf(logit - mval);
    float sum = ex;
    #pragma unroll
    for (int m = 16; m; m >>= 1) sum += __shfl_xor(sum, m);
    const float lse  = mval + logf(sum);
    const float logp = logit - lse;
    const float p    = expf(logp);
    float epl = p * logp;
    #pragma unroll
    for (int m = 16; m; m >>= 1) epl += __shfl_xor(epl, m);
    const float entropy = -epl;
    const float tok_logp = __shfl(logp, midx, 32);

    if (lane == 0) {
        out[b]             = (float)midx;
        out[B_SZ + b]      = entropy;
        out[2 * B_SZ + b]  = tok_logp;
    }
}

// ---------------------------------------------------------------------------
extern "C" void kernel_launch(void* const* d_in, const int* in_sizes, int n_in,
                              void* d_out, int out_size, void* d_ws, size_t ws_size,
                              hipStream_t stream)
{
    const float* snd    = (const float*)d_in[0];
    const float* ph     = (const float*)d_in[1];   // 2 x B x H
    const float* co     = (const float*)d_in[2];
    const float* pmsg   = (const float*)d_in[3];
    const float* Wk     = (const float*)d_in[4];
    const float* bk     = (const float*)d_in[5];
    const float* i2hW0  = (const float*)d_in[6];
    const float* i2hb0  = (const float*)d_in[7];
    const float* h2hW0  = (const float*)d_in[8];
    const float* h2hb0  = (const float*)d_in[9];
    const float* hWW0   = (const float*)d_in[10];
    const float* hWb0   = (const float*)d_in[11];
    const float* hUW0   = (const float*)d_in[12];
    const float* hUb0   = (const float*)d_in[13];
    const float* i2hW1  = (const float*)d_in[14];
    const float* i2hb1  = (const float*)d_in[15];
    const float* h2hW1  = (const float*)d_in[16];
    const float* h2hb1  = (const float*)d_in[17];
    const float* hWW1   = (const float*)d_in[18];
    const float* hWb1   = (const float*)d_in[19];
    const float* hUW1   = (const float*)d_in[20];
    const float* hUb1   = (const float*)d_in[21];
    const float* outW   = (const float*)d_in[22];
    const float* outb   = (const float*)d_in[23];

    float* out = (float*)d_out;
    float* h0out = out + (size_t)3 * B_SZ + (size_t)B_SZ * VOCAB;
    float* h1out = h0out + (size_t)B_SZ * H_SZ;

    const float* h0prev = ph;
    const float* h1prev = ph + (size_t)B_SZ * H_SZ;

    // ---- workspace carve-up ----
    char* p = (char*)d_ws;
    auto alloc_f = [&](size_t n) { float* r = (float*)p; p += n * 4; return r; };
    auto alloc_h = [&](size_t n) { u16* r = (u16*)p; p += ((n * 2 + 15) & ~15ull); return r; };

    float* qbuf   = alloc_f((size_t)B_SZ * 256);
    float* cbar   = alloc_f((size_t)B_SZ * 256);
    float* gxc    = alloc_f((size_t)B_SZ * 1536);
    float* ghc    = alloc_f((size_t)B_SZ * 1536);
    u16* rin_hi = alloc_h((size_t)B_SZ * 384);          // blocked, KT=12
    u16* rin_lo = alloc_h((size_t)B_SZ * 384);
    u16* php_hi = alloc_h((size_t)2 * B_SZ * 512);      // blocked, KT=16 (both cells)
    u16* php_lo = alloc_h((size_t)2 * B_SZ * 512);
    u16* h0i_hi = alloc_h((size_t)B_SZ * 512);          // blocked, KT=16
    u16* h0i_lo = alloc_h((size_t)B_SZ * 512);
    u16* W0x_hi = alloc_h((size_t)1536 * 384);
    u16* W0x_lo = alloc_h((size_t)1536 * 384);
    u16* W0h_hi = alloc_h((size_t)1536 * 512);
    u16* W0h_lo = alloc_h((size_t)1536 * 512);
    u16* W1x_hi = alloc_h((size_t)1536 * 512);
    u16* W1x_lo = alloc_h((size_t)1536 * 512);
    u16* W1h_hi = alloc_h((size_t)1536 * 512);
    u16* W1h_lo = alloc_h((size_t)1536 * 512);
    float* b0x = alloc_f(1536);
    float* b0h = alloc_f(1536);
    float* b1x = alloc_f(1536);
    float* b1h = alloc_f(1536);

    // ---- weight prep (independent of activations) ----
    transpose_split_w<<<dim3(24, 6), 256, 0, stream>>>(i2hW0, hWW0, 1024, 512, 384, W0x_hi, W0x_lo);
    transpose_split_w<<<dim3(24, 8), 256, 0, stream>>>(h2hW0, hUW0, 1024, 512, 512, W0h_hi, W0h_lo);
    transpose_split_w<<<dim3(24, 8), 256, 0, stream>>>(i2hW1, hWW1, 1024, 512, 512, W1x_hi, W1x_lo);
    transpose_split_w<<<dim3(24, 8), 256, 0, stream>>>(h2hW1, hUW1, 1024, 512, 512, W1h_hi, W1h_lo);
    bias_cat4_kernel<<<24, 256, 0, stream>>>(i2hb0, hWb0, b0x, h2hb0, hUb0, b0h,
                                             i2hb1, hWb1, b1x, h2hb1, hUb1, b1h);
    // prev_hidden (both cells, 8192 x 512) -> blocked split images
    split_blocked_kernel<<<2 * B_SZ * 64 / 256, 256, 0, stream>>>(ph, php_hi, php_lo);

    // ---- attention trio ----
    gemm_bt64_kernel<<<dim3(4, 64), 256, 0, stream>>>(snd, Wk, qbuf, B_SZ, 256, 128, 256);
    attn_ctx_kernel<<<B_SZ, 256, 0, stream>>>(co, qbuf, snd, pmsg, cbar, rin_hi, rin_lo);
    gemm_ctx_kernel<<<dim3(2, 64), 256, 0, stream>>>(cbar, Wk, bk, rin_hi, rin_lo);

    // ---- GRU cell 0 ----
    mfma_gemm_dual_kernel<<<768, 256, 0, stream>>>(
        rin_hi, rin_lo, W0x_hi, W0x_lo, b0x, gxc, 12,
        php_hi, php_lo, W0h_hi, W0h_lo, b0h, ghc, 16);
    gru_combine_kernel<<<B_SZ, 256, 0, stream>>>(gxc, ghc, h0prev, h0out, h0i_hi, h0i_lo);

    // ---- GRU cell 1 ----
    mfma_gemm_dual_kernel<<<768, 256, 0, stream>>>(
        h0i_hi, h0i_lo, W1x_hi, W1x_lo, b1x, gxc, 16,
        php_hi + (size_t)B_SZ * 512, php_lo + (size_t)B_SZ * 512,
        W1h_hi, W1h_lo, b1h, ghc, 16);
    gru_combine_kernel<<<B_SZ, 256, 0, stream>>>(gxc, ghc, h1prev, h1out, (u16*)nullptr, (u16*)nullptr);

    // ---- output head ----
    out_kernel<<<B_SZ / 4, 256, 0, stream>>>(h1out, outW, outb, out);
}

// Round 12
// 440.874 us; speedup vs baseline: 1.0489x; 1.0489x over previous
//
#include <hip/hip_runtime.h>
#include <hip/hip_bf16.h>
#include <math.h>

// Problem constants
#define B_SZ   4096
#define NCAND  32
#define DIN    256
#define E_SZ   128
#define H_SZ   512
#define VOCAB  32
#define LN_EPS 1e-5f

typedef unsigned short u16;
typedef unsigned int   u32;
typedef __attribute__((ext_vector_type(8))) short  short8;   // 8 bf16 (4 VGPR)
typedef __attribute__((ext_vector_type(4))) float  floatx4;  // MFMA acc

static __device__ __forceinline__ float sigmoidf_(float x) {
    return 1.0f / (1.0f + expf(-x));
}
// fp32 -> bf16 (RNE), finite inputs
static __device__ __forceinline__ u16 f2bf(float x) {
    u32 u = __float_as_uint(x);
    return (u16)((u + 0x7FFFu + ((u >> 16) & 1u)) >> 16);
}
static __device__ __forceinline__ float bfbits2f(u16 h) {
    return __uint_as_float(((u32)h) << 16);
}

// async 16B global->LDS (DMA; LDS dest = wave-uniform base + lane*16)
typedef const __attribute__((address_space(1))) unsigned int* gas_ptr;
typedef __attribute__((address_space(3)))       unsigned int* las_ptr;
static __device__ __forceinline__ void gload_lds16(const u16* g, u16* l) {
    __builtin_amdgcn_global_load_lds((gas_ptr)(const void*)g, (las_ptr)(void*)l, 16, 0, 0);
}

// Load 8 fp32, split into hi/lo bf16, store 16B each.
static __device__ __forceinline__ void split_store8(const float* __restrict__ g,
                                                    u16* __restrict__ sh,
                                                    u16* __restrict__ sl)
{
    float4 a = *(const float4*)g;
    float4 b = *(const float4*)(g + 4);
    float v[8] = {a.x, a.y, a.z, a.w, b.x, b.y, b.z, b.w};
    union { u16 us[8]; uint4 q; } hb, lb;
    #pragma unroll
    for (int j = 0; j < 8; ++j) {
        u16 h = f2bf(v[j]);
        hb.us[j] = h;
        lb.us[j] = f2bf(v[j] - bfbits2f(h));
    }
    *(uint4*)sh = hb.q;
    *(uint4*)sl = lb.q;
}

// Blocked "LDS-image" index for element (row r, col/k):
//   idx = (rtile*KT + k/32)*4096 + (r&127)*32 + (k&31)
// Each 4096-u16 image = one 128x32 linear LDS staging buffer.

// ---------------------------------------------------------------------------
// Weight prep: blocked split images from [W1 | W2] (K x N1, K x N2), N-major
// ---------------------------------------------------------------------------
__global__ __launch_bounds__(256)
void transpose_split_w(const float* __restrict__ W1, const float* __restrict__ W2,
                       int N1, int N2, int K,
                       u16* __restrict__ Wt_hi, u16* __restrict__ Wt_lo)
{
    __shared__ float t[64][68];
    const int n0 = blockIdx.x * 64, k0 = blockIdx.y * 64;
    const int tid = threadIdx.x;
    const int KT = K >> 5;

    {
        const int kl = tid >> 4, nl4 = (tid & 15) * 4;
        const int ng = n0 + nl4;
        const float* src; int col, ld;
        if (ng < N1) { src = W1; col = ng;      ld = N1; }
        else         { src = W2; col = ng - N1; ld = N2; }
        #pragma unroll
        for (int p = 0; p < 4; ++p) {
            float4 v = *(const float4*)(src + (size_t)(k0 + kl + p * 16) * ld + col);
            *(float4*)&t[kl + p * 16][nl4] = v;
        }
    }
    __syncthreads();

    const int nl = tid >> 2, kc = tid & 3;
    union { u16 us[16]; uint4 v[2]; } hb, lb;
    #pragma unroll
    for (int j = 0; j < 16; ++j) {
        float x = t[kc * 16 + j][nl];
        u16 h = f2bf(x);
        float r = x - bfbits2f(h);
        hb.us[j] = h;
        lb.us[j] = f2bf(r);
    }
    const int n  = n0 + nl;
    const int kb = k0 + kc * 16;               // multiple of 16
    const size_t off = ((size_t)(n >> 7) * KT + (kb >> 5)) * 4096
                     + (size_t)(n & 127) * 32 + (kb & 31);
    *(uint4*)(Wt_hi + off)     = hb.v[0];
    *(uint4*)(Wt_hi + off + 8) = hb.v[1];
    *(uint4*)(Wt_lo + off)     = lb.v[0];
    *(uint4*)(Wt_lo + off + 8) = lb.v[1];
}

// All four bias concats in one launch
__global__ __launch_bounds__(256)
void bias_cat4_kernel(const float* __restrict__ a0, const float* __restrict__ c0, float* __restrict__ o0,
                      const float* __restrict__ a1, const float* __restrict__ c1, float* __restrict__ o1,
                      const float* __restrict__ a2, const float* __restrict__ c2, float* __restrict__ o2,
                      const float* __restrict__ a3, const float* __restrict__ c3, float* __restrict__ o3)
{
    const int t = blockIdx.x * 256 + threadIdx.x;      // 0..6143
    const int w = t / 1536;
    const int i = t - w * 1536;
    const float* a; const float* c; float* o;
    if      (w == 0) { a = a0; c = c0; o = o0; }
    else if (w == 1) { a = a1; c = c1; o = o1; }
    else if (w == 2) { a = a2; c = c2; o = o2; }
    else             { a = a3; c = c3; o = o3; }
    o[i] = (i < 1024) ? a[i] : c[i - 1024];
}

// fp32 [M][512] row-major -> blocked split images (KT=16). grid = M*64/256.
__global__ __launch_bounds__(256)
void split_blocked_kernel(const float* __restrict__ src,
                          u16* __restrict__ hi, u16* __restrict__ lo)
{
    const int i = blockIdx.x * 256 + threadIdx.x;
    const int m = i >> 6, kq = (i & 63) << 3;
    const size_t idx = ((size_t)(m >> 7) * 16 + (kq >> 5)) * 4096
                     + (size_t)(m & 127) * 32 + (kq & 31);
    split_store8(src + (size_t)m * 512 + kq, &hi[idx], &lo[idx]);
}

// ---------------------------------------------------------------------------
// Dual split-bf16 MFMA GEMM, blocked bf16 images, global_load_lds staging,
// double-buffered. LDS 64 KB -> 2 blocks/CU.
//   C(4096x1536) = A @ W^T + bias ; acc += Ah*Wh + Ah*Wl + Al*Wh
// 1D grid of 768 blocks, XCD-chunked swizzle (bijective).
// ---------------------------------------------------------------------------
__global__ __launch_bounds__(256)
void mfma_gemm_dual_kernel(const u16* __restrict__ Axh, const u16* __restrict__ Axl,
                           const u16* __restrict__ Wxh, const u16* __restrict__ Wxl,
                           const float* __restrict__ bx, float* __restrict__ Cx, int KTx,
                           const u16* __restrict__ Ahh, const u16* __restrict__ Ahl,
                           const u16* __restrict__ Whh, const u16* __restrict__ Whl,
                           const float* __restrict__ bh, float* __restrict__ Ch, int KTh)
{
    __shared__ __align__(16) u16 sAh[2][4096];
    __shared__ __align__(16) u16 sAl[2][4096];
    __shared__ __align__(16) u16 sWh[2][4096];
    __shared__ __align__(16) u16 sWl[2][4096];

    const int tid  = threadIdx.x;
    const int lane = tid & 63;
    const int wave = tid >> 6;
    const int wm = (wave >> 1) * 64;
    const int wn = (wave & 1) * 64;
    const int r16 = lane & 15;
    const int q8  = (lane >> 4) * 8;

    // XCD-chunk swizzle: 768 blocks = 8 XCDs x 96 (bijective: f=8q+r -> r*96+q)
    const int f   = blockIdx.x;
    const int lin = (f & 7) * 96 + (f >> 3);
    const int sel = lin >= 384;
    const int r   = lin - (sel ? 384 : 0);       // 0..383
    const int mt  = r / 12;
    const int nt  = r - mt * 12;
    const int m_base = mt * 128;
    const int n_base = nt * 128;

    const u16* Ah_  = sel ? Ahh : Axh;
    const u16* Al_  = sel ? Ahl : Axl;
    const u16* Wh_  = sel ? Whh : Wxh;
    const u16* Wl_  = sel ? Whl : Wxl;
    const float* bias = sel ? bh : bx;
    float*       C    = sel ? Ch : Cx;
    const int    KT   = sel ? KTh : KTx;

    const size_t abase = (size_t)(m_base >> 7) * KT * 4096;
    const size_t wbase = (size_t)(n_base >> 7) * KT * 4096;
    const int sofs = wave * 1024;            // this wave's quarter of each image
    const int gofs = sofs + (lane << 3);     // per-lane 16B chunk (u16 units)

    floatx4 acc[4][4] = {};

    // prologue: stage k-tile 0 into buffer 0
    {
        const size_t ai = abase + gofs;
        const size_t wi = wbase + gofs;
        gload_lds16(Ah_ + ai,       &sAh[0][sofs]);
        gload_lds16(Ah_ + ai + 512, &sAh[0][sofs + 512]);
        gload_lds16(Al_ + ai,       &sAl[0][sofs]);
        gload_lds16(Al_ + ai + 512, &sAl[0][sofs + 512]);
        gload_lds16(Wh_ + wi,       &sWh[0][sofs]);
        gload_lds16(Wh_ + wi + 512, &sWh[0][sofs + 512]);
        gload_lds16(Wl_ + wi,       &sWl[0][sofs]);
        gload_lds16(Wl_ + wi + 512, &sWl[0][sofs + 512]);
    }

    int cur = 0;
    for (int kt = 0; kt < KT; ++kt) {
        // drains vmcnt(0): buf[cur] staged; all waves done reading buf[cur^1]
        __syncthreads();

        const int nxt = cur ^ 1;
        if (kt + 1 < KT) {
            const size_t ai = abase + (size_t)(kt + 1) * 4096 + gofs;
            const size_t wi = wbase + (size_t)(kt + 1) * 4096 + gofs;
            gload_lds16(Ah_ + ai,       &sAh[nxt][sofs]);
            gload_lds16(Ah_ + ai + 512, &sAh[nxt][sofs + 512]);
            gload_lds16(Al_ + ai,       &sAl[nxt][sofs]);
            gload_lds16(Al_ + ai + 512, &sAl[nxt][sofs + 512]);
            gload_lds16(Wh_ + wi,       &sWh[nxt][sofs]);
            gload_lds16(Wh_ + wi + 512, &sWh[nxt][sofs + 512]);
            gload_lds16(Wl_ + wi,       &sWl[nxt][sofs]);
            gload_lds16(Wl_ + wi + 512, &sWl[nxt][sofs + 512]);
        }

        short8 ah[4], al[4], bhf[4], blf[4];
        #pragma unroll
        for (int i = 0; i < 4; ++i) {
            const int ar = (wm + i * 16 + r16) * 32 + q8;
            ah[i] = *(const short8*)&sAh[cur][ar];
            al[i] = *(const short8*)&sAl[cur][ar];
            const int br = (wn + i * 16 + r16) * 32 + q8;
            bhf[i] = *(const short8*)&sWh[cur][br];
            blf[i] = *(const short8*)&sWl[cur][br];
        }
        #pragma unroll
        for (int i = 0; i < 4; ++i)
            #pragma unroll
            for (int j = 0; j < 4; ++j) {
                acc[i][j] = __builtin_amdgcn_mfma_f32_16x16x32_bf16(ah[i], bhf[j], acc[i][j], 0, 0, 0);
                acc[i][j] = __builtin_amdgcn_mfma_f32_16x16x32_bf16(ah[i], blf[j], acc[i][j], 0, 0, 0);
                acc[i][j] = __builtin_amdgcn_mfma_f32_16x16x32_bf16(al[i], bhf[j], acc[i][j], 0, 0, 0);
            }

        cur = nxt;
    }

    // epilogue: C/D mapping col=lane&15, row=(lane>>4)*4+reg
    const int quad = lane >> 4;
    #pragma unroll
    for (int j = 0; j < 4; ++j) {
        const int n = n_base + wn + j * 16 + r16;
        const float bv = bias[n];
        #pragma unroll
        for (int i = 0; i < 4; ++i) {
            #pragma unroll
            for (int rr = 0; rr < 4; ++rr) {
                const int m = m_base + wm + i * 16 + quad * 4 + rr;
                C[(size_t)m * 1536 + n] = acc[i][j][rr] + bv;
            }
        }
    }
}

// ---------------------------------------------------------------------------
// q = A(MxK) @ Bt(NxK)^T. 64x64x16 tiles, 4x4 micro. (q = snd @ Wk^T)
// ---------------------------------------------------------------------------
__global__ __launch_bounds__(256)
void gemm_bt64_kernel(const float* __restrict__ A, const float* __restrict__ Bt,
                      float* __restrict__ C, int M, int N, int K, int ldc)
{
    __shared__ float As[16][68];
    __shared__ float Bs[16][68];

    const int tid = threadIdx.x;
    const int bm = blockIdx.y * 64;
    const int bn = blockIdx.x * 64;
    const int tx = tid & 15, ty = tid >> 4;
    const int m0 = ty * 4, n0 = tx * 4;
    const int arow = tid >> 2, acol = (tid & 3) * 4;

    float acc[4][4] = {};

    for (int k0 = 0; k0 < K; k0 += 16) {
        float4 a4 = *(const float4*)(A  + (size_t)(bm + arow) * K + (k0 + acol));
        float4 b4 = *(const float4*)(Bt + (size_t)(bn + arow) * K + (k0 + acol));
        As[acol + 0][arow] = a4.x; As[acol + 1][arow] = a4.y;
        As[acol + 2][arow] = a4.z; As[acol + 3][arow] = a4.w;
        Bs[acol + 0][arow] = b4.x; Bs[acol + 1][arow] = b4.y;
        Bs[acol + 2][arow] = b4.z; Bs[acol + 3][arow] = b4.w;
        __syncthreads();
        #pragma unroll
        for (int k = 0; k < 16; ++k) {
            float4 av = *(const float4*)&As[k][m0];
            float4 bv = *(const float4*)&Bs[k][n0];
            float aa[4] = {av.x, av.y, av.z, av.w};
            float bb[4] = {bv.x, bv.y, bv.z, bv.w};
            #pragma unroll
            for (int i = 0; i < 4; ++i)
                #pragma unroll
                for (int j = 0; j < 4; ++j)
                    acc[i][j] = fmaf(aa[i], bb[j], acc[i][j]);
        }
        __syncthreads();
    }

    #pragma unroll
    for (int i = 0; i < 4; ++i)
        *(float4*)(C + (size_t)(bm + m0 + i) * ldc + bn + n0) =
            make_float4(acc[i][0], acc[i][1], acc[i][2], acc[i][3]);
}

// ---------------------------------------------------------------------------
// fused scores/softmax/cbar + rnn_in tail. STAGE-FREE: co read direct (L3/L2).
// ---------------------------------------------------------------------------
__global__ __launch_bounds__(256)
void attn_ctx_kernel(const float* __restrict__ co, const float* __restrict__ q,
                     const float* __restrict__ snd, const float* __restrict__ pmsg,
                     float* __restrict__ cbar,
                     u16* __restrict__ rinh, u16* __restrict__ rinl)
{
    __shared__ float s_q[DIN];
    __shared__ float s_scores[NCAND];
    __shared__ float s_w[NCAND];

    const int b   = blockIdx.x;
    const int tid = threadIdx.x;
    const float* cob = co + (size_t)b * NCAND * DIN;

    if (tid < DIN) s_q[tid] = q[(size_t)b * DIN + tid];
    __syncthreads();

    // scores[n] = sum_d co[n][d] * q[d]  (8 partials per candidate; co direct)
    {
        const int n = tid >> 3, part = tid & 7;
        const float* con = cob + n * DIN;
        float sc = 0.f;
        #pragma unroll
        for (int qq = 0; qq < 8; ++qq) {
            const int d = part * 4 + qq * 32;
            float4 cv = *(const float4*)(con + d);
            float4 qv = *(const float4*)&s_q[d];
            sc += cv.x * qv.x + cv.y * qv.y + cv.z * qv.z + cv.w * qv.w;
        }
        #pragma unroll
        for (int m = 4; m; m >>= 1) sc += __shfl_xor(sc, m);
        if (part == 0) s_scores[n] = sc;
    }
    __syncthreads();

    // softmax over 32 candidates
    if (tid < NCAND) {
        float s  = s_scores[tid];
        float mx = s;
        #pragma unroll
        for (int m = 16; m; m >>= 1) mx = fmaxf(mx, __shfl_xor(mx, m));
        float e = expf(s - mx);
        float sum = e;
        #pragma unroll
        for (int m = 16; m; m >>= 1) sum += __shfl_xor(sum, m);
        s_w[tid] = e / sum;
    }
    __syncthreads();

    // cbar[d] = sum_n w[n] * co[n][d]  (d = tid; co rows direct, L2-hot)
    {
        float cb = 0.f;
        #pragma unroll
        for (int n = 0; n < NCAND; ++n) cb = fmaf(s_w[n], cob[n * DIN + tid], cb);
        cbar[(size_t)b * DIN + tid] = cb;
    }
    {
        // rnn_in cols 128..383: [snd | pmsg] -> blocked split image
        const float x = (tid < 128) ? snd[(size_t)b * E_SZ + tid]
                                    : pmsg[(size_t)b * E_SZ + (tid - 128)];
        const int d = 128 + tid;
        const u16 h = f2bf(x);
        const u16 l = f2bf(x - bfbits2f(h));
        const size_t idx = ((size_t)(b >> 7) * 12 + (d >> 5)) * 4096
                         + (size_t)(b & 127) * 32 + (d & 31);
        rinh[idx] = h;
        rinl[idx] = l;
    }
}

// ---------------------------------------------------------------------------
// context = cbar @ Wk + bk -> rnn_in cols 0..127 (blocked split image, KT=12)
// 64x64 tiles, grid (2, 64) = 128 blocks.
// ---------------------------------------------------------------------------
__global__ __launch_bounds__(256)
void gemm_ctx_kernel(const float* __restrict__ A, const float* __restrict__ Bm,
                     const float* __restrict__ bias,
                     u16* __restrict__ rinh, u16* __restrict__ rinl)
{
    __shared__ float As[16][68];
    __shared__ float Bs[16][68];

    const int tid = threadIdx.x;
    const int bm = blockIdx.y * 64;
    const int bn = blockIdx.x * 64;
    const int tx = tid & 15, ty = tid >> 4;
    const int m0 = ty * 4, n0 = tx * 4;
    const int arow = tid >> 2, acol = (tid & 3) * 4;   // 64 rows x 16 k
    const int brow = tid >> 4, bcol = (tid & 15) * 4;  // 16 k x 64 cols
    const int K = 256, N = 128;

    float acc[4][4] = {};

    for (int k0 = 0; k0 < K; k0 += 16) {
        float4 a4 = *(const float4*)(A + (size_t)(bm + arow) * K + (k0 + acol));
        float4 b4 = *(const float4*)(Bm + (size_t)(k0 + brow) * N + (bn + bcol));
        As[acol + 0][arow] = a4.x; As[acol + 1][arow] = a4.y;
        As[acol + 2][arow] = a4.z; As[acol + 3][arow] = a4.w;
        *(float4*)&Bs[brow][bcol] = b4;
        __syncthreads();
        #pragma unroll
        for (int k = 0; k < 16; ++k) {
            float4 av = *(const float4*)&As[k][m0];
            float4 bv = *(const float4*)&Bs[k][n0];
            float aa[4] = {av.x, av.y, av.z, av.w};
            float bb[4] = {bv.x, bv.y, bv.z, bv.w};
            #pragma unroll
            for (int i = 0; i < 4; ++i)
                #pragma unroll
                for (int j = 0; j < 4; ++j)
                    acc[i][j] = fmaf(aa[i], bb[j], acc[i][j]);
        }
        __syncthreads();
    }

    const float4 bv = *(const float4*)(bias + bn + n0);
    #pragma unroll
    for (int i = 0; i < 4; ++i) {
        float o0 = acc[i][0] + bv.x, o1 = acc[i][1] + bv.y;
        float o2 = acc[i][2] + bv.z, o3 = acc[i][3] + bv.w;
        const int m = bm + m0 + i;
        const int d = bn + n0;                         // multiple of 4, < 128
        const u16 h0 = f2bf(o0), h1 = f2bf(o1), h2 = f2bf(o2), h3 = f2bf(o3);
        const u16 l0 = f2bf(o0 - bfbits2f(h0));
        const u16 l1 = f2bf(o1 - bfbits2f(h1));
        const u16 l2 = f2bf(o2 - bfbits2f(h2));
        const u16 l3 = f2bf(o3 - bfbits2f(h3));
        const size_t idx = ((size_t)(m >> 7) * 12 + (d >> 5)) * 4096
                         + (size_t)(m & 127) * 32 + (d & 31);
        uint2 hv, lv;
        hv.x = (u32)h0 | ((u32)h1 << 16); hv.y = (u32)h2 | ((u32)h3 << 16);
        lv.x = (u32)l0 | ((u32)l1 << 16); lv.y = (u32)l2 | ((u32)l3 << 16);
        *(uint2*)&rinh[idx] = hv;
        *(uint2*)&rinl[idx] = lv;
    }
}

// ---------------------------------------------------------------------------
// LN-GRU combine; optional blocked split image write of new h (KT=16)
// ---------------------------------------------------------------------------
__global__ __launch_bounds__(256)
void gru_combine_kernel(const float* __restrict__ gxc, const float* __restrict__ ghc,
                        const float* __restrict__ hprev, float* __restrict__ hout,
                        u16* __restrict__ himg_hi, u16* __restrict__ himg_lo)
{
    const int b    = blockIdx.x;
    const int tid  = threadIdx.x;
    const int lane = tid & 63, wv = tid >> 6;

    __shared__ float s_part[4][8];
    __shared__ float s_gates[1024];

    const float* gxb = gxc + (size_t)b * 1536;
    const float* ghb = ghc + (size_t)b * 1536;

    const float4 gx4 = *(const float4*)(gxb + tid * 4);
    const float4 gh4 = *(const float4*)(ghb + tid * 4);
    const float2 cx2 = *(const float2*)(gxb + 1024 + tid * 2);
    const float2 ch2 = *(const float2*)(ghb + 1024 + tid * 2);

    float v[8];
    v[0] = gx4.x + gx4.y + gx4.z + gx4.w;
    v[1] = gx4.x*gx4.x + gx4.y*gx4.y + gx4.z*gx4.z + gx4.w*gx4.w;
    v[2] = gh4.x + gh4.y + gh4.z + gh4.w;
    v[3] = gh4.x*gh4.x + gh4.y*gh4.y + gh4.z*gh4.z + gh4.w*gh4.w;
    v[4] = cx2.x + cx2.y;
    v[5] = cx2.x*cx2.x + cx2.y*cx2.y;
    v[6] = ch2.x + ch2.y;
    v[7] = ch2.x*ch2.x + ch2.y*ch2.y;

    #pragma unroll
    for (int i = 0; i < 8; ++i)
        #pragma unroll
        for (int m = 32; m; m >>= 1) v[i] += __shfl_xor(v[i], m);

    if (lane == 0) {
        #pragma unroll
        for (int i = 0; i < 8; ++i) s_part[wv][i] = v[i];
    }
    __syncthreads();

    float t[8];
    #pragma unroll
    for (int i = 0; i < 8; ++i)
        t[i] = s_part[0][i] + s_part[1][i] + s_part[2][i] + s_part[3][i];

    const float mgx = t[0] / 1024.f;
    const float rgx = 1.f / sqrtf(t[1] / 1024.f - mgx * mgx + LN_EPS);
    const float mgh = t[2] / 1024.f;
    const float rgh = 1.f / sqrtf(t[3] / 1024.f - mgh * mgh + LN_EPS);
    const float mcx = t[4] / 512.f;
    const float rcx = 1.f / sqrtf(t[5] / 512.f - mcx * mcx + LN_EPS);
    const float mch = t[6] / 512.f;
    const float rch = 1.f / sqrtf(t[7] / 512.f - mch * mch + LN_EPS);

    float4 g;
    g.x = sigmoidf_((gx4.x - mgx) * rgx + (gh4.x - mgh) * rgh);
    g.y = sigmoidf_((gx4.y - mgx) * rgx + (gh4.y - mgh) * rgh);
    g.z = sigmoidf_((gx4.z - mgx) * rgx + (gh4.z - mgh) * rgh);
    g.w = sigmoidf_((gx4.w - mgx) * rgx + (gh4.w - mgh) * rgh);
    *(float4*)&s_gates[tid * 4] = g;
    __syncthreads();

    const float2 hp2 = *(const float2*)(hprev + (size_t)b * 512 + tid * 2);
    const float z0 = s_gates[tid * 2 + 0];
    const float z1 = s_gates[tid * 2 + 1];
    const float r0 = s_gates[512 + tid * 2 + 0];
    const float r1 = s_gates[512 + tid * 2 + 1];

    const float hh0 = tanhf((cx2.x - mcx) * rcx + r0 * ((ch2.x - mch) * rch));
    const float hh1 = tanhf((cx2.y - mcx) * rcx + r1 * ((ch2.y - mch) * rch));
    const float hn0 = (1.f - z0) * hp2.x + z0 * hh0;
    const float hn1 = (1.f - z1) * hp2.y + z1 * hh1;

    *(float2*)(hout + (size_t)b * 512 + tid * 2) = make_float2(hn0, hn1);

    if (himg_hi) {
        const u16 h0b = f2bf(hn0), h1b = f2bf(hn1);
        const u16 l0b = f2bf(hn0 - bfbits2f(h0b));
        const u16 l1b = f2bf(hn1 - bfbits2f(h1b));
        const int k = tid * 2;
        const size_t idx = ((size_t)(b >> 7) * 16 + (k >> 5)) * 4096
                         + (size_t)(b & 127) * 32 + (k & 31);
        *(u32*)&himg_hi[idx] = (u32)h0b | ((u32)h1b << 16);
        *(u32*)&himg_lo[idx] = (u32)l0b | ((u32)l1b << 16);
    }
}

// ---------------------------------------------------------------------------
// output head
// ---------------------------------------------------------------------------
__global__ __launch_bounds__(256)
void out_kernel(const float* __restrict__ h1, const float* __restrict__ W,
                const float* __restrict__ bias, float* __restrict__ out)
{
    __shared__ float s_h[4][512];
    const int wave = threadIdx.x >> 6, lane = threadIdx.x & 63;
    const int b = blockIdx.x * 4 + wave;

    {
        const float4* hp = (const float4*)(h1 + (size_t)b * 512);
        float4* sp = (float4*)&s_h[wave][0];
        sp[lane]      = hp[lane];
        sp[lane + 64] = hp[lane + 64];
    }
    __syncthreads();

    const int v = lane & 31, half = lane >> 5;
    float acc = 0.f;
    {
        const float* wp = W + (size_t)half * 256 * 32 + v;
        const float* hh = &s_h[wave][half * 256];
        for (int k = 0; k < 256; ++k) acc = fmaf(hh[k], wp[(size_t)k * 32], acc);
    }
    acc += __shfl_xor(acc, 32);
    const float logit = acc + bias[v];

    if (half == 0)
        out[(size_t)3 * B_SZ + (size_t)b * VOCAB + v] = logit;

    float mval = logit; int midx = v;
    #pragma unroll
    for (int m = 16; m; m >>= 1) {
        float ov = __shfl_xor(mval, m);
        int   oi = __shfl_xor(midx, m);
        if (ov > mval || (ov == mval && oi < midx)) { mval = ov; midx = oi; }
    }
    float ex = expf(logit - mval);
    float sum = ex;
    #pragma unroll
    for (int m = 16; m; m >>= 1) sum += __shfl_xor(sum, m);
    const float lse  = mval + logf(sum);
    const float logp = logit - lse;
    const float p    = expf(logp);
    float epl = p * logp;
    #pragma unroll
    for (int m = 16; m; m >>= 1) epl += __shfl_xor(epl, m);
    const float entropy = -epl;
    const float tok_logp = __shfl(logp, midx, 32);

    if (lane == 0) {
        out[b]             = (float)midx;
        out[B_SZ + b]      = entropy;
        out[2 * B_SZ + b]  = tok_logp;
    }
}

// ---------------------------------------------------------------------------
extern "C" void kernel_launch(void* const* d_in, const int* in_sizes, int n_in,
                              void* d_out, int out_size, void* d_ws, size_t ws_size,
                              hipStream_t stream)
{
    const float* snd    = (const float*)d_in[0];
    const float* ph     = (const float*)d_in[1];   // 2 x B x H
    const float* co     = (const float*)d_in[2];
    const float* pmsg   = (const float*)d_in[3];
    const float* Wk     = (const float*)d_in[4];
    const float* bk     = (const float*)d_in[5];
    const float* i2hW0  = (const float*)d_in[6];
    const float* i2hb0  = (const float*)d_in[7];
    const float* h2hW0  = (const float*)d_in[8];
    const float* h2hb0  = (const float*)d_in[9];
    const float* hWW0   = (const float*)d_in[10];
    const float* hWb0   = (const float*)d_in[11];
    const float* hUW0   = (const float*)d_in[12];
    const float* hUb0   = (const float*)d_in[13];
    const float* i2hW1  = (const float*)d_in[14];
    const float* i2hb1  = (const float*)d_in[15];
    const float* h2hW1  = (const float*)d_in[16];
    const float* h2hb1  = (const float*)d_in[17];
    const float* hWW1   = (const float*)d_in[18];
    const float* hWb1   = (const float*)d_in[19];
    const float* hUW1   = (const float*)d_in[20];
    const float* hUb1   = (const float*)d_in[21];
    const float* outW   = (const float*)d_in[22];
    const float* outb   = (const float*)d_in[23];

    float* out = (float*)d_out;
    float* h0out = out + (size_t)3 * B_SZ + (size_t)B_SZ * VOCAB;
    float* h1out = h0out + (size_t)B_SZ * H_SZ;

    const float* h0prev = ph;
    const float* h1prev = ph + (size_t)B_SZ * H_SZ;

    // ---- workspace carve-up ----
    char* p = (char*)d_ws;
    auto alloc_f = [&](size_t n) { float* r = (float*)p; p += n * 4; return r; };
    auto alloc_h = [&](size_t n) { u16* r = (u16*)p; p += ((n * 2 + 15) & ~15ull); return r; };

    float* qbuf   = alloc_f((size_t)B_SZ * 256);
    float* cbar   = alloc_f((size_t)B_SZ * 256);
    float* gxc    = alloc_f((size_t)B_SZ * 1536);
    float* ghc    = alloc_f((size_t)B_SZ * 1536);
    u16* rin_hi = alloc_h((size_t)B_SZ * 384);          // blocked, KT=12
    u16* rin_lo = alloc_h((size_t)B_SZ * 384);
    u16* php_hi = alloc_h((size_t)2 * B_SZ * 512);      // blocked, KT=16 (both cells)
    u16* php_lo = alloc_h((size_t)2 * B_SZ * 512);
    u16* h0i_hi = alloc_h((size_t)B_SZ * 512);          // blocked, KT=16
    u16* h0i_lo = alloc_h((size_t)B_SZ * 512);
    u16* W0x_hi = alloc_h((size_t)1536 * 384);
    u16* W0x_lo = alloc_h((size_t)1536 * 384);
    u16* W0h_hi = alloc_h((size_t)1536 * 512);
    u16* W0h_lo = alloc_h((size_t)1536 * 512);
    u16* W1x_hi = alloc_h((size_t)1536 * 512);
    u16* W1x_lo = alloc_h((size_t)1536 * 512);
    u16* W1h_hi = alloc_h((size_t)1536 * 512);
    u16* W1h_lo = alloc_h((size_t)1536 * 512);
    float* b0x = alloc_f(1536);
    float* b0h = alloc_f(1536);
    float* b1x = alloc_f(1536);
    float* b1h = alloc_f(1536);

    // ---- weight prep (independent of activations) ----
    transpose_split_w<<<dim3(24, 6), 256, 0, stream>>>(i2hW0, hWW0, 1024, 512, 384, W0x_hi, W0x_lo);
    transpose_split_w<<<dim3(24, 8), 256, 0, stream>>>(h2hW0, hUW0, 1024, 512, 512, W0h_hi, W0h_lo);
    transpose_split_w<<<dim3(24, 8), 256, 0, stream>>>(i2hW1, hWW1, 1024, 512, 512, W1x_hi, W1x_lo);
    transpose_split_w<<<dim3(24, 8), 256, 0, stream>>>(h2hW1, hUW1, 1024, 512, 512, W1h_hi, W1h_lo);
    bias_cat4_kernel<<<24, 256, 0, stream>>>(i2hb0, hWb0, b0x, h2hb0, hUb0, b0h,
                                             i2hb1, hWb1, b1x, h2hb1, hUb1, b1h);
    // prev_hidden (both cells, 8192 x 512) -> blocked split images
    split_blocked_kernel<<<2 * B_SZ * 64 / 256, 256, 0, stream>>>(ph, php_hi, php_lo);

    // ---- attention trio ----
    gemm_bt64_kernel<<<dim3(4, 64), 256, 0, stream>>>(snd, Wk, qbuf, B_SZ, 256, 128, 256);
    attn_ctx_kernel<<<B_SZ, 256, 0, stream>>>(co, qbuf, snd, pmsg, cbar, rin_hi, rin_lo);
    gemm_ctx_kernel<<<dim3(2, 64), 256, 0, stream>>>(cbar, Wk, bk, rin_hi, rin_lo);

    // ---- GRU cell 0 ----
    mfma_gemm_dual_kernel<<<768, 256, 0, stream>>>(
        rin_hi, rin_lo, W0x_hi, W0x_lo, b0x, gxc, 12,
        php_hi, php_lo, W0h_hi, W0h_lo, b0h, ghc, 16);
    gru_combine_kernel<<<B_SZ, 256, 0, stream>>>(gxc, ghc, h0prev, h0out, h0i_hi, h0i_lo);

    // ---- GRU cell 1 ----
    mfma_gemm_dual_kernel<<<768, 256, 0, stream>>>(
        h0i_hi, h0i_lo, W1x_hi, W1x_lo, b1x, gxc, 16,
        php_hi + (size_t)B_SZ * 512, php_lo + (size_t)B_SZ * 512,
        W1h_hi, W1h_lo, b1h, ghc, 16);
    gru_combine_kernel<<<B_SZ, 256, 0, stream>>>(gxc, ghc, h1prev, h1out, (u16*)nullptr, (u16*)nullptr);

    // ---- output head ----
    out_kernel<<<B_SZ / 4, 256, 0, stream>>>(h1out, outW, outb, out);
}